// Round 2
// baseline (237.007 us; speedup 1.0000x reference)
//
#include <hip/hip_runtime.h>
#include <math.h>

// T=512, B=256, D=256, H=4. Wires 2,3 input-independent -> closed form.
// R6: hoist the per-t table (hcf/hob) out of the gemm into a one-block setup
// kernel (was: recomputed by all 2048 blocks behind a __syncthreads barrier,
// ~2k cyc of branchy libm each + 20KB LDS). Gemm is now a pure streaming
// kernel: double-buffered 4-row groups, table values gathered early from L2.
// Scan: unchanged contractive chunked-parallel recurrence (verified).
#define TT 512
#define BB 256
#define DD 256
#define INV2PI 0.15915494309189535f
#define CHUNK 32
#define WARM 24
#define NCH (TT / CHUNK)        // 16

typedef float v2f __attribute__((ext_vector_type(2)));
typedef float v4f __attribute__((ext_vector_type(4)));

__device__ __forceinline__ v2f pkfma(v2f a, v2f b, v2f c) {
    return __builtin_elementwise_fma(a, b, c);
}
__device__ __forceinline__ v2f cos2(v2f a) {
    v2f r;
    r.x = __builtin_amdgcn_cosf(a.x);   // v_cos_f32: cos(2*pi*x)
    r.y = __builtin_amdgcn_cosf(a.y);
    return r;
}
// sigmoid(x), |x|<=1. Odd Taylor deg-7: max err ~2e-5.
__device__ __forceinline__ v2f sig2(v2f x) {
    v2f u = x * x;
    v2f p = pkfma(u, (v2f)(-2.1081349e-4f), (v2f)(2.0833333e-3f));
    p = pkfma(u, p, (v2f)(-2.0833333e-2f));
    p = pkfma(u, p, (v2f)(0.25f));
    return pkfma(x, p, (v2f)(0.5f));
}
// tanh(x), |x|<=~2.5: Pade CF4, err <2e-5.
__device__ __forceinline__ v2f tanh2(v2f x) {
    v2f u = x * x;
    v2f n = pkfma(u + (v2f)(105.0f), u, (v2f)(945.0f));
    v2f d = pkfma(pkfma(u, (v2f)(15.0f), (v2f)(420.0f)), u, (v2f)(945.0f));
    v2f r;
    r.x = __builtin_amdgcn_rcpf(d.x);
    r.y = __builtin_amdgcn_rcpf(d.y);
    return x * n * r;
}

// Multi-value butterfly: sum p[0..7] across 64 lanes, 10 shuffles.
// Lane l ends with the sum for value v = 4*(l&1) + 2*((l>>1)&1) + ((l>>2)&1).
__device__ __forceinline__ float reduce8(float p[8], int lane) {
    const bool b0 = lane & 1;
#pragma unroll
    for (int k = 0; k < 4; ++k) {
        float send = b0 ? p[k] : p[k + 4];
        float q = __shfl_xor(send, 1, 64);
        p[k] = (b0 ? p[k + 4] : p[k]) + q;
    }
    const bool b1 = lane & 2;
#pragma unroll
    for (int k = 0; k < 2; ++k) {
        float send = b1 ? p[k] : p[k + 2];
        float q = __shfl_xor(send, 2, 64);
        p[k] = (b1 ? p[k + 2] : p[k]) + q;
    }
    const bool b2 = lane & 4;
    {
        float send = b2 ? p[0] : p[1];
        float q = __shfl_xor(send, 4, 64);
        p[0] = (b2 ? p[1] : p[0]) + q;
    }
    p[0] += __shfl_xor(p[0], 8, 64);
    p[0] += __shfl_xor(p[0], 16, 64);
    p[0] += __shfl_xor(p[0], 32, 64);
    return p[0];
}

// Kernel 0: one block computes the per-t tables once.
// hcf[t*8 + g*2 + wire] = (b+phi + h2*W[.,258] + h3*W[.,259]) * INV2PI
// hob[t*2 + w]          = h_{t+1}[w+2]  (deterministic wires)
__global__ __launch_bounds__(256) void qlstm_setup(
    const float* __restrict__ Wf, const float* __restrict__ bf, const float* __restrict__ pf,
    const float* __restrict__ Wi, const float* __restrict__ bi, const float* __restrict__ pi,
    const float* __restrict__ Wu, const float* __restrict__ bu, const float* __restrict__ pu,
    const float* __restrict__ Wo, const float* __restrict__ bo, const float* __restrict__ po,
    float* __restrict__ hcf, float* __restrict__ hob) {
    const int tid = threadIdx.x;
    const float* Ws[4] = {Wf, Wi, Wu, Wo};
    const float* Bs[4] = {bf, bi, bu, bo};
    const float* Ps[4] = {pf, pi, pu, po};

    float l2fc[2], Scc[2], occ[2], ricc[2];
#pragma unroll
    for (int w = 0; w < 2; ++w) {
        const int q = w + 2;
        float fv = 1.0f / (1.0f + expf(-cosf(Ps[0][q])));
        float iv = 1.0f / (1.0f + expf(-cosf(Ps[1][q])));
        float gv = tanhf(cosf(Ps[2][q]));
        float ov = 1.0f / (1.0f + expf(-cosf(Ps[3][q])));
        l2fc[w] = log2f(fv);
        Scc[w] = iv * gv;
        occ[w] = ov;
        ricc[w] = 1.0f / (1.0f - fv);
    }
    float bb[8];
#pragma unroll
    for (int g = 0; g < 4; ++g)
#pragma unroll
        for (int wire = 0; wire < 2; ++wire) bb[g * 2 + wire] = Bs[g][wire] + Ps[g][wire];

    for (int t = tid; t < TT; t += 256) {
        float h2 = occ[0] * tanhf(Scc[0] * (1.0f - exp2f((float)t * l2fc[0])) * ricc[0]);
        float h3 = occ[1] * tanhf(Scc[1] * (1.0f - exp2f((float)t * l2fc[1])) * ricc[1]);
        float ho2 = occ[0] * tanhf(Scc[0] * (1.0f - exp2f((float)(t + 1) * l2fc[0])) * ricc[0]);
        float ho3 = occ[1] * tanhf(Scc[1] * (1.0f - exp2f((float)(t + 1) * l2fc[1])) * ricc[1]);
#pragma unroll
        for (int g = 0; g < 4; ++g)
#pragma unroll
            for (int wire = 0; wire < 2; ++wire)
                hcf[t * 8 + g * 2 + wire] =
                    (bb[g * 2 + wire] + h2 * Ws[g][wire * 260 + 258] + h3 * Ws[g][wire * 260 + 259]) * INV2PI;
        hob[t * 2] = ho2;
        hob[t * 2 + 1] = ho3;
    }
}

// Kernel A: Z[t,b,j] = (x[t,b,:].W_j)*INV2PI + hcf[t][j]; out[t][b][2..3] from hob.
// Pure streaming: one wave per row, double-buffered 4-row groups.
__global__ __launch_bounds__(256) void qlstm_gemm(
    const float* __restrict__ x,
    const float* __restrict__ Wf, const float* __restrict__ Wi,
    const float* __restrict__ Wu, const float* __restrict__ Wo,
    const float* __restrict__ hcf, const float* __restrict__ hob,
    float* __restrict__ Z, float* __restrict__ out) {
    const int tid = threadIdx.x;
    const int lane = tid & 63;
    const int wid = (blockIdx.x * 256 + tid) >> 6;  // 0..8191
    const int tbase = wid >> 8;                     // t of row wid (k=0); t(r)=tbase+k*32
    const float* Ws[4] = {Wf, Wi, Wu, Wo};

    float4 wv[8];
#pragma unroll
    for (int g = 0; g < 4; ++g)
#pragma unroll
        for (int wire = 0; wire < 2; ++wire)
            wv[g * 2 + wire] = *(const float4*)(Ws[g] + wire * 260 + 4 * lane);
    const int v = ((lane & 1) << 2) | (lane & 2) | ((lane >> 2) & 1);

    v4f xcur[4], xnxt[4];
#pragma unroll
    for (int j = 0; j < 4; ++j)
        xcur[j] = *(const v4f*)(x + (size_t)(wid + j * 8192) * DD + 4 * lane);

#pragma unroll
    for (int k = 0; k < 16; k += 4) {
        // early table gathers (L2-resident 16KB table; arrive before stores need them)
        float hv[4];
        float2 hb;
        if (lane < 8) {
#pragma unroll
            for (int j = 0; j < 4; ++j) hv[j] = hcf[(tbase + (k + j) * 32) * 8 + v];
        } else if (lane < 12) {
            hb = *(const float2*)(hob + (tbase + (k + lane - 8) * 32) * 2);
        }
        // prefetch next 4-row group while reducing this one
        if (k < 12) {
#pragma unroll
            for (int j = 0; j < 4; ++j)
                xnxt[j] = *(const v4f*)(x + (size_t)(wid + (k + 4 + j) * 8192) * DD + 4 * lane);
        }
#pragma unroll
        for (int j = 0; j < 4; ++j) {
            float p[8];
#pragma unroll
            for (int m = 0; m < 8; ++m)
                p[m] = xcur[j].x * wv[m].x + xcur[j].y * wv[m].y + xcur[j].z * wv[m].z +
                       xcur[j].w * wv[m].w;
            float s = reduce8(p, lane);
            if (lane < 8)
                Z[(size_t)(wid + (k + j) * 8192) * 8 + v] = s * INV2PI + hv[j];
        }
        if (lane >= 8 && lane < 12)
            *(float2*)(out + (size_t)(wid + (k + lane - 8) * 8192) * 4 + 2) = hb;
        if (k < 12) {
#pragma unroll
            for (int j = 0; j < 4; ++j) xcur[j] = xnxt[j];
        }
    }
}

// Kernel B: chunked-parallel scan. Grid = NCH*4 blocks x 64 threads.
// block -> (chunk, bgroup); lane = batch elem. Warm-up from h=c=0 at
// tw = max(0, t0-WARM), emit CHUNK steps.
__global__ __launch_bounds__(64) void qlstm_scan(
    const float* __restrict__ Z,
    const float* __restrict__ Wf, const float* __restrict__ pf,
    const float* __restrict__ Wi, const float* __restrict__ pi,
    const float* __restrict__ Wu, const float* __restrict__ pu,
    const float* __restrict__ Wo, const float* __restrict__ po,
    float* __restrict__ out) {
    const int tid = threadIdx.x;
    const int chunk = blockIdx.x >> 2;
    const int b = (blockIdx.x & 3) * 64 + tid;
    const float* Ws[4] = {Wf, Wi, Wu, Wo};
    const float* Ps[4] = {pf, pi, pu, po};

    // deterministic finals for the hx / cx rows (only chunk NCH-1 uses them)
    float cd[2], hd[2];
#pragma unroll
    for (int w = 0; w < 2; ++w) {
        const int q = w + 2;
        float fv = 1.0f / (1.0f + expf(-cosf(Ps[0][q])));
        float iv = 1.0f / (1.0f + expf(-cosf(Ps[1][q])));
        float gv = tanhf(cosf(Ps[2][q]));
        float ov = 1.0f / (1.0f + expf(-cosf(Ps[3][q])));
        float l2f = log2f(fv);
        float S = iv * gv;
        float ric = 1.0f / (1.0f - fv);
        cd[w] = S * (1.0f - exp2f(512.0f * l2f)) * ric;
        hd[w] = ov * tanhf(cd[w]);
    }

    v2f wa[4], wb[4];
#pragma unroll
    for (int g = 0; g < 4; ++g) {
        wa[g].x = Ws[g][256] * INV2PI;
        wa[g].y = Ws[g][260 + 256] * INV2PI;
        wb[g].x = Ws[g][257] * INV2PI;
        wb[g].y = Ws[g][260 + 257] * INV2PI;
    }

    const int t0 = chunk * CHUNK;
    const int tw = (t0 - WARM > 0) ? (t0 - WARM) : 0;  // chunk 0 -> 0
    const int len = t0 + CHUNK - tw;                   // 32 or 56 (%8 == 0)

    v2f h = (v2f)(0.0f), c = (v2f)(0.0f);
    const float* Zb = Z + (size_t)b * 8;  // row t at +t*2048 floats
    float* outp = out + (size_t)b * 4;
    v4f zbuf[8][2];
#pragma unroll
    for (int s = 0; s < 8; ++s) {
        zbuf[s][0] = *(const v4f*)(Zb + (size_t)(tw + s) * 2048);
        zbuf[s][1] = *(const v4f*)(Zb + (size_t)(tw + s) * 2048 + 4);
    }

#pragma unroll 8
    for (int s = 0; s < len; ++s) {
        const int t = tw + s;
        const int slot = s & 7;
        v4f zA = zbuf[slot][0], zB = zbuf[slot][1];
        if (s + 8 < len) {
            zbuf[slot][0] = *(const v4f*)(Zb + (size_t)(t + 8) * 2048);
            zbuf[slot][1] = *(const v4f*)(Zb + (size_t)(t + 8) * 2048 + 4);
        }
        v2f zf = {zA.x, zA.y}, zi = {zA.z, zA.w}, zu = {zB.x, zB.y}, zo = {zB.z, zB.w};
        v2f h0s = (v2f)(h.x), h1s = (v2f)(h.y);
        v2f af = pkfma(h0s, wa[0], pkfma(h1s, wb[0], zf));
        v2f ai = pkfma(h0s, wa[1], pkfma(h1s, wb[1], zi));
        v2f au = pkfma(h0s, wa[2], pkfma(h1s, wb[2], zu));
        v2f ao = pkfma(h0s, wa[3], pkfma(h1s, wb[3], zo));
        v2f f = sig2(cos2(af));
        v2f i = sig2(cos2(ai));
        v2f g = tanh2(cos2(au));
        v2f o = sig2(cos2(ao));
        c = pkfma(f, c, i * g);
        v2f th = tanh2(c);
        h = o * th;
        if (t >= t0)
            *(v2f*)(outp + (size_t)t * (BB * 4)) = h;  // cols 0,1 (2,3 by gemm)
    }

    if (chunk == NCH - 1) {
        *(float4*)(out + (size_t)TT * BB * 4 + (size_t)b * 4) =
            make_float4(h.x, h.y, hd[0], hd[1]);
        *(float4*)(out + (size_t)TT * BB * 4 + (size_t)BB * 4 + (size_t)b * 4) =
            make_float4(c.x, c.y, cd[0], cd[1]);
    }
}

extern "C" void kernel_launch(void* const* d_in, const int* in_sizes, int n_in,
                              void* d_out, int out_size, void* d_ws, size_t ws_size,
                              hipStream_t stream) {
    (void)in_sizes; (void)n_in; (void)out_size; (void)ws_size;
    const float* x  = (const float*)d_in[0];
    const float* Wf = (const float*)d_in[1];
    const float* bf = (const float*)d_in[2];
    const float* pf = (const float*)d_in[3];
    const float* Wi = (const float*)d_in[4];
    const float* bi = (const float*)d_in[5];
    const float* pi = (const float*)d_in[6];
    const float* Wu = (const float*)d_in[7];
    const float* bu = (const float*)d_in[8];
    const float* pu = (const float*)d_in[9];
    const float* Wo = (const float*)d_in[10];
    const float* bo = (const float*)d_in[11];
    const float* po = (const float*)d_in[12];
    float* out = (float*)d_out;
    float* Z = (float*)d_ws;                     // T*B*8*4 = 4 MiB
    float* hcf = Z + (size_t)TT * BB * 8;        // T*8 floats (16 KB)
    float* hob = hcf + (size_t)TT * 8;           // T*2 floats (4 KB)

    qlstm_setup<<<1, 256, 0, stream>>>(Wf, bf, pf, Wi, bi, pi, Wu, bu, pu,
                                       Wo, bo, po, hcf, hob);
    qlstm_gemm<<<2048, 256, 0, stream>>>(x, Wf, Wi, Wu, Wo, hcf, hob, Z, out);
    qlstm_scan<<<NCH * 4, 64, 0, stream>>>(Z, Wf, pf, Wi, pi, Wu, pu, Wo, po, out);
}

// Round 3
// 233.037 us; speedup vs baseline: 1.0170x; 1.0170x over previous
//
#include <hip/hip_runtime.h>
#include <math.h>

// T=512, B=256, D=256, H=4. Wires 2,3 input-independent -> closed form.
// R7: 2-dispatch structure. Gemm is a pure stream (x.W -> Z, no tables, no out
// writes). Scan recomputes its own 56-entry per-t table in a prologue (LDS,
// lane-uniform broadcast reads) and emits out as ONE float4 per (t,b):
// cols 0,1 = recurrent h, cols 2,3 = deterministic-wire h (closed form).
// Kills the setup dispatch + its graph gap, and the split half-line out writes.
// Scan core: unchanged contractive chunked-parallel recurrence (verified).
#define TT 512
#define BB 256
#define DD 256
#define INV2PI 0.15915494309189535f
#define CHUNK 32
#define WARM 24
#define NCH (TT / CHUNK)        // 16
#define MAXLEN (CHUNK + WARM)   // 56

typedef float v2f __attribute__((ext_vector_type(2)));
typedef float v4f __attribute__((ext_vector_type(4)));

__device__ __forceinline__ v2f pkfma(v2f a, v2f b, v2f c) {
    return __builtin_elementwise_fma(a, b, c);
}
__device__ __forceinline__ v2f cos2(v2f a) {
    v2f r;
    r.x = __builtin_amdgcn_cosf(a.x);   // v_cos_f32: cos(2*pi*x)
    r.y = __builtin_amdgcn_cosf(a.y);
    return r;
}
// sigmoid(x), |x|<=1. Odd Taylor deg-7: max err ~2e-5.
__device__ __forceinline__ v2f sig2(v2f x) {
    v2f u = x * x;
    v2f p = pkfma(u, (v2f)(-2.1081349e-4f), (v2f)(2.0833333e-3f));
    p = pkfma(u, p, (v2f)(-2.0833333e-2f));
    p = pkfma(u, p, (v2f)(0.25f));
    return pkfma(x, p, (v2f)(0.5f));
}
// tanh(x), |x|<=~2.5: Pade CF4, err <2e-5.
__device__ __forceinline__ v2f tanh2(v2f x) {
    v2f u = x * x;
    v2f n = pkfma(u + (v2f)(105.0f), u, (v2f)(945.0f));
    v2f d = pkfma(pkfma(u, (v2f)(15.0f), (v2f)(420.0f)), u, (v2f)(945.0f));
    v2f r;
    r.x = __builtin_amdgcn_rcpf(d.x);
    r.y = __builtin_amdgcn_rcpf(d.y);
    return x * n * r;
}

// Multi-value butterfly: sum p[0..7] across 64 lanes, 10 shuffles.
// Lane l ends with the sum for value v = 4*(l&1) + 2*((l>>1)&1) + ((l>>2)&1).
__device__ __forceinline__ float reduce8(float p[8], int lane) {
    const bool b0 = lane & 1;
#pragma unroll
    for (int k = 0; k < 4; ++k) {
        float send = b0 ? p[k] : p[k + 4];
        float q = __shfl_xor(send, 1, 64);
        p[k] = (b0 ? p[k + 4] : p[k]) + q;
    }
    const bool b1 = lane & 2;
#pragma unroll
    for (int k = 0; k < 2; ++k) {
        float send = b1 ? p[k] : p[k + 2];
        float q = __shfl_xor(send, 2, 64);
        p[k] = (b1 ? p[k + 2] : p[k]) + q;
    }
    const bool b2 = lane & 4;
    {
        float send = b2 ? p[0] : p[1];
        float q = __shfl_xor(send, 4, 64);
        p[0] = (b2 ? p[1] : p[0]) + q;
    }
    p[0] += __shfl_xor(p[0], 8, 64);
    p[0] += __shfl_xor(p[0], 16, 64);
    p[0] += __shfl_xor(p[0], 32, 64);
    return p[0];
}

// Kernel A: Z[t,b,j] = (x[t,b,:] . W_j) * INV2PI. Pure streaming, one wave per
// row (64 lanes x float4 = whole row), double-buffered 4-row groups.
__global__ __launch_bounds__(256) void qlstm_gemm(
    const float* __restrict__ x,
    const float* __restrict__ Wf, const float* __restrict__ Wi,
    const float* __restrict__ Wu, const float* __restrict__ Wo,
    float* __restrict__ Z) {
    const int tid = threadIdx.x;
    const int lane = tid & 63;
    const int wid = (blockIdx.x * 256 + tid) >> 6;  // 0..8191
    const float* Ws[4] = {Wf, Wi, Wu, Wo};

    float4 wv[8];
#pragma unroll
    for (int g = 0; g < 4; ++g)
#pragma unroll
        for (int wire = 0; wire < 2; ++wire)
            wv[g * 2 + wire] = *(const float4*)(Ws[g] + wire * 260 + 4 * lane);
    const int v = ((lane & 1) << 2) | (lane & 2) | ((lane >> 2) & 1);

    v4f xcur[4], xnxt[4];
#pragma unroll
    for (int j = 0; j < 4; ++j)
        xcur[j] = *(const v4f*)(x + (size_t)(wid + j * 8192) * DD + 4 * lane);

#pragma unroll
    for (int k = 0; k < 16; k += 4) {
        // prefetch next 4-row group while reducing this one
        if (k < 12) {
#pragma unroll
            for (int j = 0; j < 4; ++j)
                xnxt[j] = *(const v4f*)(x + (size_t)(wid + (k + 4 + j) * 8192) * DD + 4 * lane);
        }
#pragma unroll
        for (int j = 0; j < 4; ++j) {
            float p[8];
#pragma unroll
            for (int m = 0; m < 8; ++m)
                p[m] = xcur[j].x * wv[m].x + xcur[j].y * wv[m].y + xcur[j].z * wv[m].z +
                       xcur[j].w * wv[m].w;
            float s = reduce8(p, lane);
            if (lane < 8)
                Z[(size_t)(wid + (k + j) * 8192) * 8 + v] = s * INV2PI;
        }
        if (k < 12) {
#pragma unroll
            for (int j = 0; j < 4; ++j) xcur[j] = xnxt[j];
        }
    }
}

// Kernel B: chunked-parallel scan. Grid = NCH*4 blocks x 64 threads.
// block -> (chunk, bgroup); lane = batch elem. Warm-up from h=c=0 at
// tw = max(0, t0-WARM), emit CHUNK steps. Prologue: per-block LDS table of the
// lane-uniform angle constants hcf[t][8] and deterministic h_{t+1}[2,3].
__global__ __launch_bounds__(64) void qlstm_scan(
    const float* __restrict__ Z,
    const float* __restrict__ Wf, const float* __restrict__ bf, const float* __restrict__ pf,
    const float* __restrict__ Wi, const float* __restrict__ bi, const float* __restrict__ pi,
    const float* __restrict__ Wu, const float* __restrict__ bu, const float* __restrict__ pu,
    const float* __restrict__ Wo, const float* __restrict__ bo, const float* __restrict__ po,
    float* __restrict__ out) {
    __shared__ float hcf_s[MAXLEN * 8];   // 1.75 KB
    __shared__ float hob_s[MAXLEN * 2];   // 448 B
    const int tid = threadIdx.x;
    const int chunk = blockIdx.x >> 2;
    const int b = (blockIdx.x & 3) * 64 + tid;
    const float* Ws[4] = {Wf, Wi, Wu, Wo};
    const float* Bs[4] = {bf, bi, bu, bo};
    const float* Ps[4] = {pf, pi, pu, po};

    const int t0 = chunk * CHUNK;
    const int tw = (t0 - WARM > 0) ? (t0 - WARM) : 0;  // chunk 0 -> 0
    const int len = t0 + CHUNK - tw;                   // 32 or 56 (%8 == 0)

    // per-wire deterministic constants (computed redundantly by all threads)
    float l2fc[2], Scc[2], occ2[2], ricc[2];
#pragma unroll
    for (int w = 0; w < 2; ++w) {
        const int q = w + 2;
        float fv = 1.0f / (1.0f + expf(-cosf(Ps[0][q])));
        float iv = 1.0f / (1.0f + expf(-cosf(Ps[1][q])));
        float gv = tanhf(cosf(Ps[2][q]));
        float ov = 1.0f / (1.0f + expf(-cosf(Ps[3][q])));
        l2fc[w] = log2f(fv);
        Scc[w] = iv * gv;
        occ2[w] = ov;
        ricc[w] = 1.0f / (1.0f - fv);
    }
    // deterministic finals for the hx / cx rows (only chunk NCH-1 uses them)
    float cd[2], hd[2];
#pragma unroll
    for (int w = 0; w < 2; ++w) {
        cd[w] = Scc[w] * (1.0f - exp2f(512.0f * l2fc[w])) * ricc[w];
        hd[w] = occ2[w] * tanhf(cd[w]);
    }
    // per-t table: thread i handles t = tw+i
    if (tid < len) {
        const int t = tw + tid;
        float h2 = occ2[0] * tanhf(Scc[0] * (1.0f - exp2f((float)t * l2fc[0])) * ricc[0]);
        float h3 = occ2[1] * tanhf(Scc[1] * (1.0f - exp2f((float)t * l2fc[1])) * ricc[1]);
        float ho2 = occ2[0] * tanhf(Scc[0] * (1.0f - exp2f((float)(t + 1) * l2fc[0])) * ricc[0]);
        float ho3 = occ2[1] * tanhf(Scc[1] * (1.0f - exp2f((float)(t + 1) * l2fc[1])) * ricc[1]);
#pragma unroll
        for (int g = 0; g < 4; ++g)
#pragma unroll
            for (int wire = 0; wire < 2; ++wire)
                hcf_s[tid * 8 + g * 2 + wire] =
                    (Bs[g][wire] + Ps[g][wire] + h2 * Ws[g][wire * 260 + 258] +
                     h3 * Ws[g][wire * 260 + 259]) * INV2PI;
        hob_s[tid * 2] = ho2;
        hob_s[tid * 2 + 1] = ho3;
    }

    v2f wa[4], wb[4];
#pragma unroll
    for (int g = 0; g < 4; ++g) {
        wa[g].x = Ws[g][256] * INV2PI;
        wa[g].y = Ws[g][260 + 256] * INV2PI;
        wb[g].x = Ws[g][257] * INV2PI;
        wb[g].y = Ws[g][260 + 257] * INV2PI;
    }

    __syncthreads();

    v2f h = (v2f)(0.0f), c = (v2f)(0.0f);
    const float* Zb = Z + (size_t)b * 8;  // row t at +t*2048 floats
    float* outp = out + (size_t)b * 4;
    v4f zbuf[8][2];
#pragma unroll
    for (int s = 0; s < 8; ++s) {
        zbuf[s][0] = *(const v4f*)(Zb + (size_t)(tw + s) * 2048);
        zbuf[s][1] = *(const v4f*)(Zb + (size_t)(tw + s) * 2048 + 4);
    }

#pragma unroll 8
    for (int s = 0; s < len; ++s) {
        const int t = tw + s;
        const int slot = s & 7;
        v4f zA = zbuf[slot][0], zB = zbuf[slot][1];
        if (s + 8 < len) {
            zbuf[slot][0] = *(const v4f*)(Zb + (size_t)(t + 8) * 2048);
            zbuf[slot][1] = *(const v4f*)(Zb + (size_t)(t + 8) * 2048 + 4);
        }
        // lane-uniform angle constants (LDS broadcast, off the dependent chain)
        v2f hcf_f = *(const v2f*)&hcf_s[s * 8 + 0];
        v2f hcf_i = *(const v2f*)&hcf_s[s * 8 + 2];
        v2f hcf_u = *(const v2f*)&hcf_s[s * 8 + 4];
        v2f hcf_o = *(const v2f*)&hcf_s[s * 8 + 6];
        v2f zf = {zA.x, zA.y}, zi = {zA.z, zA.w}, zu = {zB.x, zB.y}, zo = {zB.z, zB.w};
        zf += hcf_f; zi += hcf_i; zu += hcf_u; zo += hcf_o;
        v2f h0s = (v2f)(h.x), h1s = (v2f)(h.y);
        v2f af = pkfma(h0s, wa[0], pkfma(h1s, wb[0], zf));
        v2f ai = pkfma(h0s, wa[1], pkfma(h1s, wb[1], zi));
        v2f au = pkfma(h0s, wa[2], pkfma(h1s, wb[2], zu));
        v2f ao = pkfma(h0s, wa[3], pkfma(h1s, wb[3], zo));
        v2f f = sig2(cos2(af));
        v2f i = sig2(cos2(ai));
        v2f g = tanh2(cos2(au));
        v2f o = sig2(cos2(ao));
        c = pkfma(f, c, i * g);
        v2f th = tanh2(c);
        h = o * th;
        if (t >= t0) {
            v4f o4;
            o4.x = h.x;
            o4.y = h.y;
            o4.z = hob_s[s * 2];
            o4.w = hob_s[s * 2 + 1];
            *(v4f*)(outp + (size_t)t * (BB * 4)) = o4;  // full row: coalesced 16B
        }
    }

    if (chunk == NCH - 1) {
        *(float4*)(out + (size_t)TT * BB * 4 + (size_t)b * 4) =
            make_float4(h.x, h.y, hd[0], hd[1]);
        *(float4*)(out + (size_t)TT * BB * 4 + (size_t)BB * 4 + (size_t)b * 4) =
            make_float4(c.x, c.y, cd[0], cd[1]);
    }
}

extern "C" void kernel_launch(void* const* d_in, const int* in_sizes, int n_in,
                              void* d_out, int out_size, void* d_ws, size_t ws_size,
                              hipStream_t stream) {
    (void)in_sizes; (void)n_in; (void)out_size; (void)ws_size;
    const float* x  = (const float*)d_in[0];
    const float* Wf = (const float*)d_in[1];
    const float* bf = (const float*)d_in[2];
    const float* pf = (const float*)d_in[3];
    const float* Wi = (const float*)d_in[4];
    const float* bi = (const float*)d_in[5];
    const float* pi = (const float*)d_in[6];
    const float* Wu = (const float*)d_in[7];
    const float* bu = (const float*)d_in[8];
    const float* pu = (const float*)d_in[9];
    const float* Wo = (const float*)d_in[10];
    const float* bo = (const float*)d_in[11];
    const float* po = (const float*)d_in[12];
    float* out = (float*)d_out;
    float* Z = (float*)d_ws;  // T*B*8*4 = 4 MiB

    qlstm_gemm<<<2048, 256, 0, stream>>>(x, Wf, Wi, Wu, Wo, Z);
    qlstm_scan<<<NCH * 4, 64, 0, stream>>>(Z, Wf, bf, pf, Wi, bi, pi, Wu, bu, pu,
                                           Wo, bo, po, out);
}